// Round 19
// baseline (419.196 us; speedup 1.0000x reference)
//
#include <hip/hip_runtime.h>

typedef int int32x4 __attribute__((ext_vector_type(4)));

// ---------------------------------------------------------------------------
// Blocked-preswizzled operand layout (r7/r12, verified):
//   16384-B blocks, blk = rowblk*(K/128)+kblk
//   stored[row][c] = orig[row][c ^ (row&7)]  (row 0..127, c = 16-B chunk 0..7)
// ---------------------------------------------------------------------------

// fused prep: y=0 maxabs(W1), y=1 maxabs(W2), y=2 quant x -> blocked int8
__global__ void prep_kernel(const float* __restrict__ W1,
                            const float* __restrict__ W2,
                            const float* __restrict__ x, int n4,
                            int Kx, int kshiftx,
                            const float* __restrict__ s1,
                            unsigned* __restrict__ mx, int* __restrict__ xq) {
    int i0 = blockIdx.x * blockDim.x + threadIdx.x;
    int stride = gridDim.x * blockDim.x;
    if (blockIdx.y < 2) {
        const float4* x4 = (const float4*)(blockIdx.y ? W2 : W1);
        float m = 0.f;
        for (int j = i0; j < n4; j += stride) {
            float4 v = x4[j];
            m = fmaxf(m, fmaxf(fmaxf(fabsf(v.x), fabsf(v.y)),
                               fmaxf(fabsf(v.z), fabsf(v.w))));
        }
#pragma unroll
        for (int off = 32; off; off >>= 1)
            m = fmaxf(m, __shfl_down(m, off, 64));
        __shared__ float wm[4];
        int ln = threadIdx.x & 63, wv = threadIdx.x >> 6;
        if (ln == 0) wm[wv] = m;
        __syncthreads();
        if (threadIdx.x == 0) {
            float bm = fmaxf(fmaxf(wm[0], wm[1]), fmaxf(wm[2], wm[3]));
            atomicMax(mx + blockIdx.y, __float_as_uint(bm));  // nonneg: bit order ok
        }
    } else {
        float s = s1[0];
        for (int o = i0; o < n4; o += stride) {
            int blk = o >> 12;            // 4096 int-groups per 16 KB block
            int i = o & 4095;
            int row = i >> 5;             // 32 groups per 128-B row
            int c = (i >> 2) & 7;         // stored 16-B chunk
            int b4 = i & 3;               // float4 within chunk
            int rowblk = blk >> kshiftx;
            int kblk = blk & ((1 << kshiftx) - 1);
            int co = c ^ (row & 7);       // original chunk (inverse swizzle)
            long srcoff = (long)(rowblk * 128 + row) * Kx + (kblk << 7) + (co << 4) + (b4 << 2);
            float4 f = *(const float4*)(x + srcoff);
            int a = (int)fminf(fmaxf(rintf(f.x / s), -8.f), 7.f);
            int b = (int)fminf(fmaxf(rintf(f.y / s), -8.f), 7.f);
            int cc = (int)fminf(fmaxf(rintf(f.z / s), -8.f), 7.f);
            int d = (int)fminf(fmaxf(rintf(f.w / s), -8.f), 7.f);
            xq[o] = (a & 255) | ((b & 255) << 8) | ((cc & 255) << 16) | ((d & 255) << 24);
        }
    }
}

// merged W-quant: y=0 -> W1 (K=K1), y=1 -> W2 (K=K2); scale = mx[y]/7
__global__ void quantW_kernel(const float* __restrict__ W1,
                              const float* __restrict__ W2, int n4,
                              int K1, int ks1, int K2, int ks2,
                              const unsigned* __restrict__ mx,
                              int* __restrict__ w1q, int* __restrict__ w2q) {
    const int y = blockIdx.y;
    const float* src = y ? W2 : W1;
    int* out = y ? w2q : w1q;
    const int K = y ? K2 : K1;
    const int kshift = y ? ks2 : ks1;
    float s = __uint_as_float(mx[y]) / 7.0f;
    int i0 = blockIdx.x * blockDim.x + threadIdx.x;
    int stride = gridDim.x * blockDim.x;
    for (int o = i0; o < n4; o += stride) {
        int blk = o >> 12;
        int i = o & 4095;
        int row = i >> 5;
        int c = (i >> 2) & 7;
        int b4 = i & 3;
        int rowblk = blk >> kshift;
        int kblk = blk & ((1 << kshift) - 1);
        int co = c ^ (row & 7);
        long srcoff = (long)(rowblk * 128 + row) * K + (kblk << 7) + (co << 4) + (b4 << 2);
        float4 f = *(const float4*)(src + srcoff);
        int a = (int)fminf(fmaxf(rintf(f.x / s), -8.f), 7.f);
        int b = (int)fminf(fmaxf(rintf(f.y / s), -8.f), 7.f);
        int cc = (int)fminf(fmaxf(rintf(f.z / s), -8.f), 7.f);
        int d = (int)fminf(fmaxf(rintf(f.w / s), -8.f), 7.f);
        out[o] = (a & 255) | ((b & 255) << 8) | ((cc & 255) << 16) | ((d & 255) << 24);
    }
}

// ---------------------------------------------------------------------------
// int8 GEMM — r12 structure with A-FRAGMENTS DIRECT FROM GLOBAL (the only
// change). Rationale: r12 is LDS-BW-saturated (96 KB LDS traffic per
// block-K-tile / 62 B/cy = 1548 cy = the measured 1553 cy/tile). A-panels
// are L2-resident (shared by all same-row co-resident blocks), so A frags
// are per-lane 16-B global loads using the SAME address formula as the LDS
// read (blocked-preswizzled layout). LDS now carries only B: 16 KB stage +
// 32 KB frag reads = 48 KB/tile -> model ~774 cy/tile.
// B path (stage + swizzled ds_read_b128, 0 conflicts) byte-identical to r12.
// ---------------------------------------------------------------------------
template <bool FIRST>
__global__ __launch_bounds__(256, 2)
void gemm_i8_kernel(const char* __restrict__ A, const char* __restrict__ B,
                    int N, int nkt,
                    const float* __restrict__ sa_ptr,
                    const float* __restrict__ wmax_ptr,
                    const float* __restrict__ bias,
                    const float* __restrict__ s2_ptr,
                    char* __restrict__ out8, float* __restrict__ outf) {
    __shared__ __align__(16) char lB[128 * 128];   // 16 KiB, B only

    const int tid = threadIdx.x;
    const int wv = tid >> 6, ln = tid & 63;
    const int lnlo = ln & 15, lnhi = ln >> 4;
    const int wr = wv >> 1, wc = wv & 1;

    int32x4 acc[4][4] = {};

    // blocked operand bases: block index = rowblk*nkt + kt
    const char* pa = A + ((size_t)blockIdx.y * nkt << 14);
    const char* pb = B + ((size_t)blockIdx.x * nkt << 14);

    // Per-lane A fragment addresses. row = wr*64+mf*16+lnlo => row&7 = lnlo&7,
    // so swizzled chunk = (kk*4+lnhi)^(lnlo&7) is per-lane constant per kk;
    // mf contributes an immediate offset mf*2048.
    const int abase = (wr * 64 + lnlo) * 128;
    const int aoff0 = abase + ((lnhi ^ (lnlo & 7)) << 4);        // kk = 0
    const int aoff1 = abase + (((4 + lnhi) ^ (lnlo & 7)) << 4);  // kk = 1

    for (int kt = 0; kt < nkt; ++kt) {
        const char* pat = pa + ((size_t)kt << 14);

        // ---- A fragments: direct per-lane global loads (L2-resident) ----
        int32x4 af[4][2];
#pragma unroll
        for (int mf = 0; mf < 4; ++mf) {
            af[mf][0] = *(const int32x4*)(pat + aoff0 + mf * 2048);
            af[mf][1] = *(const int32x4*)(pat + aoff1 + mf * 2048);
        }

        // ---- B stage: contiguous 16 KB copy (r12 verbatim) ----
#pragma unroll
        for (int r = 0; r < 4; ++r) {
            int off = (r * 256 + tid) * 16;
            int lbase = (r * 256 + wv * 64) * 16;  // wave-uniform base (+ln*16 by HW)
            __builtin_amdgcn_global_load_lds(
                (const __attribute__((address_space(1))) void*)(pb + ((size_t)kt << 14) + off),
                (__attribute__((address_space(3))) void*)(lB + lbase), 16, 0, 0);
        }
        __syncthreads();

        // ---- B fragments from LDS (swizzled read, measured 0 conflicts) ----
        int32x4 bf[4][2];
#pragma unroll
        for (int nf = 0; nf < 4; ++nf)
#pragma unroll
            for (int kk = 0; kk < 2; ++kk) {
                int col = wc * 64 + nf * 16 + lnlo;
                int ch = kk * 4 + lnhi;
                bf[nf][kk] = *(const int32x4*)(lB + col * 128 + ((ch ^ (col & 7)) * 16));
            }

        // ---- MFMA ----
#pragma unroll
        for (int kk = 0; kk < 2; ++kk)
#pragma unroll
            for (int mf = 0; mf < 4; ++mf)
#pragma unroll
                for (int nf = 0; nf < 4; ++nf)
                    acc[mf][nf] = __builtin_amdgcn_mfma_i32_16x16x64_i8(
                        af[mf][kk], bf[nf][kk], acc[mf][nf], 0, 0, 0);
        __syncthreads();
    }

    // ---- epilogue (verified r1-r18 mapping) ----
    float sa = sa_ptr[0];
    float sw = wmax_ptr[0] / 7.0f;  // weight_scale (bits of maxabs as float)
    float sab = sa * sw;
    float s2v = FIRST ? s2_ptr[0] : 0.f;

    // hq destination block (GEMM1): [mblk][fblk] = [blockIdx.y][blockIdx.x]
    char* hblk = FIRST ? out8 + (((size_t)blockIdx.y * gridDim.x + blockIdx.x) << 14)
                       : nullptr;

#pragma unroll
    for (int nf = 0; nf < 4; ++nf) {
        int lc = wc * 64 + nf * 16 + lnlo;               // local col 0..127
        long col = (long)blockIdx.x * 128 + lc;          // global col
        float bq = rintf(bias[col] / sab) * sab;         // Int32Bias fake-quant
#pragma unroll
        for (int mf = 0; mf < 4; ++mf) {
            int lr0 = wr * 64 + mf * 16 + (lnhi << 2);   // local row base
#pragma unroll
            for (int i = 0; i < 4; ++i) {
                int lr = lr0 + i;
                float h = sab * (float)acc[mf][nf][i] + bq;
                if constexpr (FIRST) {
                    h = fmaxf(h, 0.f);
                    float qv = fminf(fmaxf(rintf(h / s2v), 0.f), 15.f);
                    // blocked-preswizzled store: stored[lr][c]=orig[lr][c^(lr&7)]
                    hblk[lr * 128 + (((lc >> 4) ^ (lr & 7)) << 4) + (lc & 15)] =
                        (char)(int)qv;
                } else {
                    outf[((long)blockIdx.y * 128 + lr) * N + col] = h;
                }
            }
        }
    }
}

// ---------------------------------------------------------------------------
// launch
// ---------------------------------------------------------------------------
extern "C" void kernel_launch(void* const* d_in, const int* in_sizes, int n_in,
                              void* d_out, int out_size, void* d_ws, size_t ws_size,
                              hipStream_t stream) {
    const float* x  = (const float*)d_in[0];   // [4,2048,2048] -> [8192,2048]
    const float* W1 = (const float*)d_in[1];   // [8192,2048]
    const float* b1 = (const float*)d_in[2];   // [8192]
    const float* W2 = (const float*)d_in[3];   // [2048,8192]
    const float* b2 = (const float*)d_in[4];   // [2048]
    const float* s1 = (const float*)d_in[5];
    const float* s2 = (const float*)d_in[6];

    const int M = 8192, D = 2048, F = 8192;

    char* ws = (char*)d_ws;
    unsigned* mx = (unsigned*)ws;          // mx[0]=maxabs(W1), mx[1]=maxabs(W2)
    char* xq  = ws + 256;                  // [M/128][D/128][16384]
    char* w1q = xq + (size_t)M * D;        // [F/128][D/128][16384]
    char* w2q = w1q + (size_t)F * D;       // [D/128][F/128][16384]
    char* hq  = w2q + (size_t)D * F;       // [M/128][F/128][16384]

    hipMemsetAsync(d_ws, 0, 8, stream);    // zero the maxabs slots

    const int n4 = (F * D) >> 2;           // == (M*D)>>2 == (D*F)>>2
    // y=0: maxabs W1, y=1: maxabs W2, y=2: quant x (needs only s1)
    prep_kernel<<<dim3(2048, 3), 256, 0, stream>>>(
        W1, W2, x, n4, D, 4, s1, mx, (int*)xq);

    // y=0: quant W1 (K=D, kshift=4), y=1: quant W2 (K=F, kshift=6)
    quantW_kernel<<<dim3(2048, 2), 256, 0, stream>>>(
        W1, W2, n4, D, 4, F, 6, mx, (int*)w1q, (int*)w2q);

    // h_q = clip(round(relu(x_q W1_q^T + b1_q)/s2),0,15) -> blocked int8
    gemm_i8_kernel<true><<<dim3(F / 128, M / 128), 256, 0, stream>>>(
        xq, w1q, F, D / 128, s1, (const float*)mx, b1, s2, hq, nullptr);

    // out = s2*sw2 * (h_int W2_int^T) + b2_q
    gemm_i8_kernel<false><<<dim3(D / 128, M / 128), 256, 0, stream>>>(
        hq, w2q, D, F / 128, s2, (const float*)(mx + 1), b2, nullptr, nullptr,
        (float*)d_out);
}

// Round 20
// 363.883 us; speedup vs baseline: 1.1520x; 1.1520x over previous
//
#include <hip/hip_runtime.h>

typedef int int32x4 __attribute__((ext_vector_type(4)));

// ---------------------------------------------------------------------------
// Blocked-preswizzled operand layout (r7/r12, verified):
//   16384-B blocks, blk = rowblk*(K/128)+kblk
//   stored[row][c] = orig[row][c ^ (row&7)]  (row 0..127, c = 16-B chunk 0..7)
// = the exact LDS image the GEMM builds, so staging is a contiguous 16 KB
// copy (rule #21) and the swizzled ds_read_b128 pattern measures 0 conflicts.
// ---------------------------------------------------------------------------

// fused prep: y=0 maxabs(W1), y=1 maxabs(W2), y=2 quant x -> blocked int8
__global__ void prep_kernel(const float* __restrict__ W1,
                            const float* __restrict__ W2,
                            const float* __restrict__ x, int n4,
                            int Kx, int kshiftx,
                            const float* __restrict__ s1,
                            unsigned* __restrict__ mx, int* __restrict__ xq) {
    int i0 = blockIdx.x * blockDim.x + threadIdx.x;
    int stride = gridDim.x * blockDim.x;
    if (blockIdx.y < 2) {
        const float4* x4 = (const float4*)(blockIdx.y ? W2 : W1);
        float m = 0.f;
        for (int j = i0; j < n4; j += stride) {
            float4 v = x4[j];
            m = fmaxf(m, fmaxf(fmaxf(fabsf(v.x), fabsf(v.y)),
                               fmaxf(fabsf(v.z), fabsf(v.w))));
        }
#pragma unroll
        for (int off = 32; off; off >>= 1)
            m = fmaxf(m, __shfl_down(m, off, 64));
        __shared__ float wm[4];
        int ln = threadIdx.x & 63, wv = threadIdx.x >> 6;
        if (ln == 0) wm[wv] = m;
        __syncthreads();
        if (threadIdx.x == 0) {
            float bm = fmaxf(fmaxf(wm[0], wm[1]), fmaxf(wm[2], wm[3]));
            atomicMax(mx + blockIdx.y, __float_as_uint(bm));  // nonneg: bit order ok
        }
    } else {
        float s = s1[0];
        for (int o = i0; o < n4; o += stride) {
            int blk = o >> 12;            // 4096 int-groups per 16 KB block
            int i = o & 4095;
            int row = i >> 5;             // 32 groups per 128-B row
            int c = (i >> 2) & 7;         // stored 16-B chunk
            int b4 = i & 3;               // float4 within chunk
            int rowblk = blk >> kshiftx;
            int kblk = blk & ((1 << kshiftx) - 1);
            int co = c ^ (row & 7);       // original chunk (inverse swizzle)
            long srcoff = (long)(rowblk * 128 + row) * Kx + (kblk << 7) + (co << 4) + (b4 << 2);
            float4 f = *(const float4*)(x + srcoff);
            int a = (int)fminf(fmaxf(rintf(f.x / s), -8.f), 7.f);
            int b = (int)fminf(fmaxf(rintf(f.y / s), -8.f), 7.f);
            int cc = (int)fminf(fmaxf(rintf(f.z / s), -8.f), 7.f);
            int d = (int)fminf(fmaxf(rintf(f.w / s), -8.f), 7.f);
            xq[o] = (a & 255) | ((b & 255) << 8) | ((cc & 255) << 16) | ((d & 255) << 24);
        }
    }
}

// merged W-quant: y=0 -> W1 (K=K1), y=1 -> W2 (K=K2); scale = mx[y]/7
__global__ void quantW_kernel(const float* __restrict__ W1,
                              const float* __restrict__ W2, int n4,
                              int K1, int ks1, int K2, int ks2,
                              const unsigned* __restrict__ mx,
                              int* __restrict__ w1q, int* __restrict__ w2q) {
    const int y = blockIdx.y;
    const float* src = y ? W2 : W1;
    int* out = y ? w2q : w1q;
    const int K = y ? K2 : K1;
    const int kshift = y ? ks2 : ks1;
    float s = __uint_as_float(mx[y]) / 7.0f;
    int i0 = blockIdx.x * blockDim.x + threadIdx.x;
    int stride = gridDim.x * blockDim.x;
    for (int o = i0; o < n4; o += stride) {
        int blk = o >> 12;
        int i = o & 4095;
        int row = i >> 5;
        int c = (i >> 2) & 7;
        int b4 = i & 3;
        int rowblk = blk >> kshift;
        int kblk = blk & ((1 << kshift) - 1);
        int co = c ^ (row & 7);
        long srcoff = (long)(rowblk * 128 + row) * K + (kblk << 7) + (co << 4) + (b4 << 2);
        float4 f = *(const float4*)(src + srcoff);
        int a = (int)fminf(fmaxf(rintf(f.x / s), -8.f), 7.f);
        int b = (int)fminf(fmaxf(rintf(f.y / s), -8.f), 7.f);
        int cc = (int)fminf(fmaxf(rintf(f.z / s), -8.f), 7.f);
        int d = (int)fminf(fmaxf(rintf(f.w / s), -8.f), 7.f);
        out[o] = (a & 255) | ((b & 255) << 8) | ((cc & 255) << 16) | ((d & 255) << 24);
    }
}

// ---------------------------------------------------------------------------
// int8 GEMM (r12 verbatim — best measured: 151.5 µs/dispatch, MfmaUtil 42%,
// 0 bank conflicts, ~3.3 blocks/CU). C[m,n] = sum_k A[m,k]*B[n,k], operands
// in blocked-preswizzled layout. 128x128 tile, BK=128 B, 4 waves (2x2),
// single-buffer 32 KiB LDS, 16x16x64 MFMA, contiguous 16 KB staging,
// 2 barriers/K-tile. FIRST epilogue writes hq in the same blocked layout.
// Survived 14 structural alternatives (schedules r2/r3/r4/r10, tiles r6,
// occupancy r8/r9, MFMA shape r5/r11, fp8 r13-r16, VALU offload r7,
// locality r18, A-from-global r19) — all null or worse.
// ---------------------------------------------------------------------------
template <bool FIRST>
__global__ __launch_bounds__(256, 2)
void gemm_i8_kernel(const char* __restrict__ A, const char* __restrict__ B,
                    int N, int nkt,
                    const float* __restrict__ sa_ptr,
                    const float* __restrict__ wmax_ptr,
                    const float* __restrict__ bias,
                    const float* __restrict__ s2_ptr,
                    char* __restrict__ out8, float* __restrict__ outf) {
    __shared__ __align__(16) char lA[128 * 128];
    __shared__ __align__(16) char lB[128 * 128];

    const int tid = threadIdx.x;
    const int wv = tid >> 6, ln = tid & 63;
    const int lnlo = ln & 15, lnhi = ln >> 4;
    const int wr = wv >> 1, wc = wv & 1;

    int32x4 acc[4][4] = {};

    // blocked operand bases: block index = rowblk*nkt + kt
    const char* pa = A + ((size_t)blockIdx.y * nkt << 14);
    const char* pb = B + ((size_t)blockIdx.x * nkt << 14);

    for (int kt = 0; kt < nkt; ++kt) {
        // ---- stage: contiguous 16 KB copy per operand ----
#pragma unroll
        for (int r = 0; r < 4; ++r) {
            int off = (r * 256 + tid) * 16;
            int lbase = (r * 256 + wv * 64) * 16;  // wave-uniform base (+ln*16 by HW)
            __builtin_amdgcn_global_load_lds(
                (const __attribute__((address_space(1))) void*)(pa + off),
                (__attribute__((address_space(3))) void*)(lA + lbase), 16, 0, 0);
            __builtin_amdgcn_global_load_lds(
                (const __attribute__((address_space(1))) void*)(pb + off),
                (__attribute__((address_space(3))) void*)(lB + lbase), 16, 0, 0);
        }
        pa += 16384;
        pb += 16384;
        __syncthreads();

        // ---- LDS -> fragments (swizzled read, measured 0 conflicts) ----
        int32x4 af[4][2], bf[4][2];
#pragma unroll
        for (int mf = 0; mf < 4; ++mf)
#pragma unroll
            for (int kk = 0; kk < 2; ++kk) {
                int row = wr * 64 + mf * 16 + lnlo;
                int ch = kk * 4 + lnhi;
                af[mf][kk] = *(const int32x4*)(lA + row * 128 + ((ch ^ (row & 7)) * 16));
            }
#pragma unroll
        for (int nf = 0; nf < 4; ++nf)
#pragma unroll
            for (int kk = 0; kk < 2; ++kk) {
                int col = wc * 64 + nf * 16 + lnlo;
                int ch = kk * 4 + lnhi;
                bf[nf][kk] = *(const int32x4*)(lB + col * 128 + ((ch ^ (col & 7)) * 16));
            }

        // ---- MFMA ----
#pragma unroll
        for (int kk = 0; kk < 2; ++kk)
#pragma unroll
            for (int mf = 0; mf < 4; ++mf)
#pragma unroll
                for (int nf = 0; nf < 4; ++nf)
                    acc[mf][nf] = __builtin_amdgcn_mfma_i32_16x16x64_i8(
                        af[mf][kk], bf[nf][kk], acc[mf][nf], 0, 0, 0);
        __syncthreads();
    }

    // ---- epilogue ----
    float sa = sa_ptr[0];
    float sw = wmax_ptr[0] / 7.0f;  // weight_scale (bits of maxabs as float)
    float sab = sa * sw;
    float s2v = FIRST ? s2_ptr[0] : 0.f;

    // hq destination block (GEMM1): [mblk][fblk] = [blockIdx.y][blockIdx.x]
    char* hblk = FIRST ? out8 + (((size_t)blockIdx.y * gridDim.x + blockIdx.x) << 14)
                       : nullptr;

#pragma unroll
    for (int nf = 0; nf < 4; ++nf) {
        int lc = wc * 64 + nf * 16 + lnlo;               // local col 0..127
        long col = (long)blockIdx.x * 128 + lc;          // global col
        float bq = rintf(bias[col] / sab) * sab;         // Int32Bias fake-quant
#pragma unroll
        for (int mf = 0; mf < 4; ++mf) {
            int lr0 = wr * 64 + mf * 16 + (lnhi << 2);   // local row base
#pragma unroll
            for (int i = 0; i < 4; ++i) {
                int lr = lr0 + i;
                float h = sab * (float)acc[mf][nf][i] + bq;
                if constexpr (FIRST) {
                    h = fmaxf(h, 0.f);
                    float qv = fminf(fmaxf(rintf(h / s2v), 0.f), 15.f);
                    // blocked-preswizzled store: stored[lr][c]=orig[lr][c^(lr&7)]
                    hblk[lr * 128 + (((lc >> 4) ^ (lr & 7)) << 4) + (lc & 15)] =
                        (char)(int)qv;
                } else {
                    outf[((long)blockIdx.y * 128 + lr) * N + col] = h;
                }
            }
        }
    }
}

// ---------------------------------------------------------------------------
// launch
// ---------------------------------------------------------------------------
extern "C" void kernel_launch(void* const* d_in, const int* in_sizes, int n_in,
                              void* d_out, int out_size, void* d_ws, size_t ws_size,
                              hipStream_t stream) {
    const float* x  = (const float*)d_in[0];   // [4,2048,2048] -> [8192,2048]
    const float* W1 = (const float*)d_in[1];   // [8192,2048]
    const float* b1 = (const float*)d_in[2];   // [8192]
    const float* W2 = (const float*)d_in[3];   // [2048,8192]
    const float* b2 = (const float*)d_in[4];   // [2048]
    const float* s1 = (const float*)d_in[5];
    const float* s2 = (const float*)d_in[6];

    const int M = 8192, D = 2048, F = 8192;

    char* ws = (char*)d_ws;
    unsigned* mx = (unsigned*)ws;          // mx[0]=maxabs(W1), mx[1]=maxabs(W2)
    char* xq  = ws + 256;                  // [M/128][D/128][16384]
    char* w1q = xq + (size_t)M * D;        // [F/128][D/128][16384]
    char* w2q = w1q + (size_t)F * D;       // [D/128][F/128][16384]
    char* hq  = w2q + (size_t)D * F;       // [M/128][F/128][16384]

    hipMemsetAsync(d_ws, 0, 8, stream);    // zero the maxabs slots

    const int n4 = (F * D) >> 2;           // == (M*D)>>2 == (D*F)>>2
    // y=0: maxabs W1, y=1: maxabs W2, y=2: quant x (needs only s1)
    prep_kernel<<<dim3(2048, 3), 256, 0, stream>>>(
        W1, W2, x, n4, D, 4, s1, mx, (int*)xq);

    // y=0: quant W1 (K=D, kshift=4), y=1: quant W2 (K=F, kshift=6)
    quantW_kernel<<<dim3(2048, 2), 256, 0, stream>>>(
        W1, W2, n4, D, 4, F, 6, mx, (int*)w1q, (int*)w2q);

    // h_q = clip(round(relu(x_q W1_q^T + b1_q)/s2),0,15) -> blocked int8
    gemm_i8_kernel<true><<<dim3(F / 128, M / 128), 256, 0, stream>>>(
        xq, w1q, F, D / 128, s1, (const float*)mx, b1, s2, hq, nullptr);

    // out = s2*sw2 * (h_int W2_int^T) + b2_q
    gemm_i8_kernel<false><<<dim3(D / 128, M / 128), 256, 0, stream>>>(
        hq, w2q, D, F / 128, s2, (const float*)(mx + 1), b2, nullptr, nullptr,
        (float*)d_out);
}